// Round 13
// baseline (56.804 us; speedup 1.0000x reference)
//
#include <hip/hip_runtime.h>
#include <hip/hip_bf16.h>

#define NB 4
#define NN 2048
#define KK 32
#define DD 64
#define R2C 0.64f

typedef __attribute__((ext_vector_type(8)))  short short8;   // 8 bf16 (4 VGPRs)
typedef __attribute__((ext_vector_type(16))) float f32x16;   // 32x32 MFMA acc

__device__ __forceinline__ unsigned short f2bf(float f) {
    __hip_bfloat16 h = __float2bfloat16(f);
    return reinterpret_cast<unsigned short&>(h);
}

#define HSTRIDE 40   // ushorts per h-row in LDS (80B = 5x16B, b128-aligned)

__device__ __forceinline__ void post_layer(const f32x16& acc, float bs,
                                           unsigned short* hl, int col, int g,
                                           float& mx, short8& f0, short8& f1) {
    float v[16];
#pragma unroll
    for (int p = 0; p < 16; ++p) v[p] = fmaxf(acc[p] + bs, 0.0f);   // base + relu
    float m = v[0];
#pragma unroll
    for (int p = 1; p < 16; ++p) m = fmaxf(m, v[p]);
    mx = fmaxf(m, __shfl_xor(m, 32));
#pragma unroll
    for (int p = 0; p < 16; ++p) {
        int r = (p & 3) + 8 * (p >> 2) + 4 * g;
        hl[r * HSTRIDE + col] = f2bf(v[p]);
    }
    const unsigned short* row = hl + col * HSTRIDE;
    f0 = *(const short8*)(row + 8 * g);
    f1 = *(const short8*)(row + 16 + 8 * g);
}

// gather 8 consecutive f32 -> bf16 short8 fragment (RNE)
__device__ __forceinline__ short8 cvt8(const float* __restrict__ p) {
    float4 a = ((const float4*)p)[0];
    float4 b = ((const float4*)p)[1];
    short8 r;
    r[0] = (short)f2bf(a.x); r[1] = (short)f2bf(a.y); r[2] = (short)f2bf(a.z); r[3] = (short)f2bf(a.w);
    r[4] = (short)f2bf(b.x); r[5] = (short)f2bf(b.y); r[6] = (short)f2bf(b.z); r[7] = (short)f2bf(b.w);
    return r;
}

__device__ __forceinline__ void l1_mfma(const short8* hf, int lane, const short8* wl, f32x16& acc) {
#pragma unroll
    for (int p = 0; p < 16; ++p) acc[p] = 0.0f;
    acc = __builtin_amdgcn_mfma_f32_32x32x16_bf16(hf[0], wl[4 * 64 + lane], acc, 0, 0, 0);
    acc = __builtin_amdgcn_mfma_f32_32x32x16_bf16(hf[1], wl[5 * 64 + lane], acc, 0, 0, 0);
}

__device__ __forceinline__ void l2_mfma(const short8* h1, const short8* h0,
                                        int lane, const short8* wl, f32x16& acc) {
#pragma unroll
    for (int p = 0; p < 16; ++p) acc[p] = 0.0f;
    acc = __builtin_amdgcn_mfma_f32_32x32x16_bf16(h1[0], wl[6 * 64 + lane], acc, 0, 0, 0);
    acc = __builtin_amdgcn_mfma_f32_32x32x16_bf16(h1[1], wl[7 * 64 + lane], acc, 0, 0, 0);
    acc = __builtin_amdgcn_mfma_f32_32x32x16_bf16(h0[0], wl[8 * 64 + lane], acc, 0, 0, 0);
    acc = __builtin_amdgcn_mfma_f32_32x32x16_bf16(h0[1], wl[9 * 64 + lane], acc, 0, 0, 0);
}

__device__ __forceinline__ void l3_mfma(const short8* h2, const short8* h1, const short8* h0,
                                        int lane, const short8* wl, f32x16& acc) {
#pragma unroll
    for (int p = 0; p < 16; ++p) acc[p] = 0.0f;
    acc = __builtin_amdgcn_mfma_f32_32x32x16_bf16(h2[0], wl[10 * 64 + lane], acc, 0, 0, 0);
    acc = __builtin_amdgcn_mfma_f32_32x32x16_bf16(h2[1], wl[11 * 64 + lane], acc, 0, 0, 0);
    acc = __builtin_amdgcn_mfma_f32_32x32x16_bf16(h1[0], wl[12 * 64 + lane], acc, 0, 0, 0);
    acc = __builtin_amdgcn_mfma_f32_32x32x16_bf16(h1[1], wl[13 * 64 + lane], acc, 0, 0, 0);
    acc = __builtin_amdgcn_mfma_f32_32x32x16_bf16(h0[0], wl[14 * 64 + lane], acc, 0, 0, 0);
    acc = __builtin_amdgcn_mfma_f32_32x32x16_bf16(h0[1], wl[15 * 64 + lane], acc, 0, 0, 0);
}

// MODE: 0 = full (writes out), 1 = front only (sink to ws), 2 = back only (inputs/sink in ws)
template<int MODE>
__device__ __forceinline__ void run_body(const float* __restrict__ x,
                                         const float* __restrict__ pos,
                                         const float* __restrict__ Wf,
                                         const float* __restrict__ bfv,
                                         const float* __restrict__ W1,
                                         const float* __restrict__ b1,
                                         const float* __restrict__ W2,
                                         const float* __restrict__ b2,
                                         const float* __restrict__ Wl,
                                         const float* __restrict__ bl,
                                         float* __restrict__ out,
                                         float* __restrict__ wsf) {
    __shared__ unsigned short hlds[4][4][32 * HSTRIDE];   // 40 KB
    __shared__ int nbrs[4][4][KK];                        // 2 KB
    __shared__ unsigned short lwf[16 * 64 * 8];           // 16 KB
    int wid = threadIdx.x >> 6, lane = threadIdx.x & 63;
    int qp = __builtin_amdgcn_readfirstlane(blockIdx.x * 4 + wid);
    int q0 = qp << 2;
    int col = lane & 31, g = lane >> 5;
    int b = q0 >> 11, n0 = q0 & (NN - 1);

    // ---- cooperative wfrag build into LDS (always: both halves need it) ----
    for (int e = threadIdx.x; e < 1024; e += 256) {
        int f = e >> 6, l = e & 63;
        int c = l & 31, g2 = l >> 5;
        unsigned short* dst = lwf + (size_t)(f * 64 + l) * 8;
#pragma unroll
        for (int j = 0; j < 8; ++j) {
            int kl = 8 * g2 + j;
            float v;
            if (f < 4)       { int rr = 16 * f + kl;             v = Wf[(64 + rr) * 32 + c] + Wf[(128 + rr) * 32 + c]; }
            else if (f < 6)  { int rr = 16 * (f - 4) + kl;       v = W1[rr * 32 + c]; }
            else if (f < 8)  { int rr = 16 * (f - 6) + kl;       v = W2[rr * 32 + c]; }
            else if (f < 10) { int rr = 32 + 16 * (f - 8) + kl;  v = W2[rr * 32 + c]; }
            else if (f < 12) { int rr = 16 * (f - 10) + kl;      v = Wl[rr * 32 + c]; }
            else if (f < 14) { int rr = 32 + 16 * (f - 12) + kl; v = Wl[rr * 32 + c]; }
            else             { int rr = 64 + 16 * (f - 14) + kl; v = Wl[rr * 32 + c]; }
            dst[j] = f2bf(v);
        }
    }

    const float* xq0 = x + (size_t)q0 * DD;
    float bs0[4], bs1[4], bs2[4], bs3[4];
    short8 xk[4][4];
    float sink = 0.0f;

    if (MODE != 2) {
        // ---- bases from RAW weights (coalesced per half-wave) ----
        bool lo = lane < 32;
        int c0 = lane & 31;
        const float* pA1 = lo ? (Wf + c0) : (W1 + 32 * 32 + c0);
        const float* pA2 = lo ? (Wf + 128 * 32 + c0) : (W1 + 32 * 32 + c0);
        float sA = lo ? -1.0f : 0.0f;
        const float* pB1 = lo ? (W2 + 64 * 32 + c0) : (Wl + 96 * 32 + c0);
        float balA = lo ? bfv[c0] : b1[c0];
        float balB = lo ? b2[c0] : bl[c0];
        float aA[4] = {balA, balA, balA, balA};
        float aB[4] = {balB, balB, balB, balB};
#pragma unroll
        for (int j0 = 0; j0 < 16; ++j0) {
            float wa[4], wb[4];
#pragma unroll
            for (int jj = 0; jj < 4; ++jj) {
                int j = 4 * j0 + jj;
                wa[jj] = fmaf(sA, pA2[j * 32], pA1[j * 32]);
                wb[jj] = pB1[j * 32];
            }
#pragma unroll
            for (int t = 0; t < 4; ++t) {
                const float* xr = xq0 + t * DD + 4 * j0;
                float x0 = xr[0], x1 = xr[1], x2 = xr[2], x3 = xr[3];
                aA[t] = fmaf(x0, wa[0], aA[t]); aA[t] = fmaf(x1, wa[1], aA[t]);
                aA[t] = fmaf(x2, wa[2], aA[t]); aA[t] = fmaf(x3, wa[3], aA[t]);
                aB[t] = fmaf(x0, wb[0], aB[t]); aB[t] = fmaf(x1, wb[1], aB[t]);
                aB[t] = fmaf(x2, wb[2], aB[t]); aB[t] = fmaf(x3, wb[3], aB[t]);
            }
        }
#pragma unroll
        for (int t = 0; t < 4; ++t) {
            bs0[t] = __shfl(aA[t], col, 64); bs1[t] = __shfl(aA[t], 32 + col, 64);
            bs2[t] = __shfl(aB[t], col, 64); bs3[t] = __shfl(aB[t], 32 + col, 64);
        }

        // ---- shared-chunk ball query (exact reference arithmetic) ----
        const float* pb = pos + (size_t)b * NN * 3;
        float qxv[4], qyv[4], qzv[4], sq4[4];
#pragma unroll
        for (int t = 0; t < 4; ++t) {
            int n = n0 + t;
            qxv[t] = pb[3 * n]; qyv[t] = pb[3 * n + 1]; qzv[t] = pb[3 * n + 2];
            sq4[t] = __fadd_rn(__fadd_rn(__fmul_rn(qxv[t], qxv[t]), __fmul_rn(qyv[t], qyv[t])),
                               __fmul_rn(qzv[t], qzv[t]));
        }
        int cnt[4] = {0, 0, 0, 0};
        unsigned long long ltmask = (1ULL << lane) - 1ULL;
        for (int m0 = 0; m0 < NN; m0 += 64) {
            if (cnt[0] >= KK && cnt[1] >= KK && cnt[2] >= KK && cnt[3] >= KK) break;
            int m = m0 + lane;
            float mx3 = pb[3 * m], my3 = pb[3 * m + 1], mz3 = pb[3 * m + 2];
            float sqm = __fadd_rn(__fadd_rn(__fmul_rn(mx3, mx3), __fmul_rn(my3, my3)), __fmul_rn(mz3, mz3));
#pragma unroll
            for (int t = 0; t < 4; ++t) {
                if (cnt[t] < KK) {
                    float dot = __fadd_rn(__fadd_rn(__fmul_rn(qxv[t], mx3), __fmul_rn(qyv[t], my3)),
                                          __fmul_rn(qzv[t], mz3));
                    float d2 = __fsub_rn(__fadd_rn(sq4[t], sqm), __fmul_rn(2.0f, dot));
                    bool hit = d2 < R2C;
                    unsigned long long mask = __ballot(hit);
                    if (hit) {
                        int p = cnt[t] + (int)__popcll(mask & ltmask);
                        if (p < KK) nbrs[wid][t][p] = m;
                    }
                    cnt[t] = __builtin_amdgcn_readfirstlane(cnt[t] + (int)__popcll(mask));
                }
            }
        }
        int nbn[4];
#pragma unroll
        for (int t = 0; t < 4; ++t) nbn[t] = nbrs[wid][t][col < cnt[t] ? col : 0];

        // ---- gather neighbor rows, cvt to bf16 in-register ----
#pragma unroll
        for (int t = 0; t < 4; ++t) {
            const float* xrow = x + (size_t)(b * NN + nbn[t]) * DD + g * 8;
#pragma unroll
            for (int kf = 0; kf < 4; ++kf) xk[t][kf] = cvt8(xrow + kf * 16);
        }

        if (MODE == 1) {
#pragma unroll
            for (int t = 0; t < 4; ++t) {
                sink += bs0[t] + bs1[t] + bs2[t] + bs3[t] + (float)nbn[t];
#pragma unroll
                for (int kf = 0; kf < 4; ++kf)
                    sink += (float)xk[t][kf][0] + (float)xk[t][kf][7];
            }
        }
    } else {
        // MODE 2: fabricate inputs from clean ws poison region (deterministic)
        const float* src = wsf + 262144;          // byte offset 1 MB, never written
#pragma unroll
        for (int t = 0; t < 4; ++t) {
            bs0[t] = src[lane + t];      bs1[t] = src[64 + lane + t];
            bs2[t] = src[128 + lane + t]; bs3[t] = src[192 + lane + t];
        }
        const short8* s8 = (const short8*)(src + 1024);
#pragma unroll
        for (int t = 0; t < 4; ++t)
#pragma unroll
            for (int kf = 0; kf < 4; ++kf)
                xk[t][kf] = s8[(lane * 17 + t * 4 + kf) & 511];
    }

    __syncthreads();     // lwf ready

    if (MODE == 1) {
        wsf[(size_t)blockIdx.x * 256 + threadIdx.x] = sink;
        return;
    }

    const short8* wl = (const short8*)lwf;
    unsigned short* hl0 = hlds[wid][0];
    unsigned short* hl1 = hlds[wid][1];
    unsigned short* hl2 = hlds[wid][2];
    unsigned short* hl3 = hlds[wid][3];

    f32x16 a0, a1, a2, a3;
    float mx0[4], mx1[4], mx2[4];
    short8 h0f[4][2], h1f[4][2], h2f[4][2];

    // ---- L0 (staggered) ----
#pragma unroll
    for (int p = 0; p < 16; ++p) { a0[p] = 0.0f; a1[p] = 0.0f; a2[p] = 0.0f; a3[p] = 0.0f; }
#pragma unroll
    for (int f = 0; f < 4; ++f) a0 = __builtin_amdgcn_mfma_f32_32x32x16_bf16(xk[0][f], wl[f * 64 + lane], a0, 0, 0, 0);
#pragma unroll
    for (int f = 0; f < 4; ++f) a1 = __builtin_amdgcn_mfma_f32_32x32x16_bf16(xk[1][f], wl[f * 64 + lane], a1, 0, 0, 0);
    post_layer(a0, bs0[0], hl0, col, g, mx0[0], h0f[0][0], h0f[0][1]);
#pragma unroll
    for (int f = 0; f < 4; ++f) a2 = __builtin_amdgcn_mfma_f32_32x32x16_bf16(xk[2][f], wl[f * 64 + lane], a2, 0, 0, 0);
    post_layer(a1, bs0[1], hl1, col, g, mx0[1], h0f[1][0], h0f[1][1]);
#pragma unroll
    for (int f = 0; f < 4; ++f) a3 = __builtin_amdgcn_mfma_f32_32x32x16_bf16(xk[3][f], wl[f * 64 + lane], a3, 0, 0, 0);
    post_layer(a2, bs0[2], hl2, col, g, mx0[2], h0f[2][0], h0f[2][1]);
    post_layer(a3, bs0[3], hl3, col, g, mx0[3], h0f[3][0], h0f[3][1]);

    // ---- L1 ----
    l1_mfma(h0f[0], lane, wl, a0);
    l1_mfma(h0f[1], lane, wl, a1);
    post_layer(a0, bs1[0], hl0, col, g, mx1[0], h1f[0][0], h1f[0][1]);
    l1_mfma(h0f[2], lane, wl, a2);
    post_layer(a1, bs1[1], hl1, col, g, mx1[1], h1f[1][0], h1f[1][1]);
    l1_mfma(h0f[3], lane, wl, a3);
    post_layer(a2, bs1[2], hl2, col, g, mx1[2], h1f[2][0], h1f[2][1]);
    post_layer(a3, bs1[3], hl3, col, g, mx1[3], h1f[3][0], h1f[3][1]);

    // ---- L2 ----
    l2_mfma(h1f[0], h0f[0], lane, wl, a0);
    l2_mfma(h1f[1], h0f[1], lane, wl, a1);
    post_layer(a0, bs2[0], hl0, col, g, mx2[0], h2f[0][0], h2f[0][1]);
    l2_mfma(h1f[2], h0f[2], lane, wl, a2);
    post_layer(a1, bs2[1], hl1, col, g, mx2[1], h2f[1][0], h2f[1][1]);
    l2_mfma(h1f[3], h0f[3], lane, wl, a3);
    post_layer(a2, bs2[2], hl2, col, g, mx2[2], h2f[2][0], h2f[2][1]);
    post_layer(a3, bs2[3], hl3, col, g, mx2[3], h2f[3][0], h2f[3][1]);

    // ---- L3 (no relu) ----
    float m3[4];
    l3_mfma(h2f[0], h1f[0], h0f[0], lane, wl, a0);
    l3_mfma(h2f[1], h1f[1], h0f[1], lane, wl, a1);
    {
        float m = a0[0] + bs3[0];
#pragma unroll
        for (int p = 1; p < 16; ++p) m = fmaxf(m, a0[p] + bs3[0]);
        m3[0] = fmaxf(m, __shfl_xor(m, 32));
    }
    l3_mfma(h2f[2], h1f[2], h0f[2], lane, wl, a2);
    {
        float m = a1[0] + bs3[1];
#pragma unroll
        for (int p = 1; p < 16; ++p) m = fmaxf(m, a1[p] + bs3[1]);
        m3[1] = fmaxf(m, __shfl_xor(m, 32));
    }
    l3_mfma(h2f[3], h1f[3], h0f[3], lane, wl, a3);
    {
        float m = a2[0] + bs3[2];
#pragma unroll
        for (int p = 1; p < 16; ++p) m = fmaxf(m, a2[p] + bs3[2]);
        m3[2] = fmaxf(m, __shfl_xor(m, 32));
    }
    {
        float m = a3[0] + bs3[3];
#pragma unroll
        for (int p = 1; p < 16; ++p) m = fmaxf(m, a3[p] + bs3[3]);
        m3[3] = fmaxf(m, __shfl_xor(m, 32));
    }

    if (MODE == 0) {
#pragma unroll
        for (int t = 0; t < 4; ++t) {
            float* o = out + (size_t)(q0 + t) * 192;
            if (g == 0) {
                o[col]      = m3[t];
                o[32 + col] = mx2[t];
                o[64 + col] = mx1[t];
                o[96 + col] = mx0[t];
            }
            o[128 + lane] = xq0[t * DD + lane];   // x passthrough
        }
    } else {  // MODE == 2: sink to ws
        float s2 = 0.0f;
#pragma unroll
        for (int t = 0; t < 4; ++t) s2 += m3[t] + mx2[t] + mx1[t] + mx0[t];
        wsf[524288 + (size_t)blockIdx.x * 256 + threadIdx.x] = s2;
    }
}

__global__ __launch_bounds__(256, 2) void fused_full(const float* __restrict__ x, const float* __restrict__ pos,
                                                     const float* __restrict__ Wf, const float* __restrict__ bfv,
                                                     const float* __restrict__ W1, const float* __restrict__ b1,
                                                     const float* __restrict__ W2, const float* __restrict__ b2,
                                                     const float* __restrict__ Wl, const float* __restrict__ bl,
                                                     float* __restrict__ out, float* __restrict__ wsf) {
    run_body<0>(x, pos, Wf, bfv, W1, b1, W2, b2, Wl, bl, out, wsf);
}

__global__ __launch_bounds__(256, 2) void abl_front(const float* __restrict__ x, const float* __restrict__ pos,
                                                    const float* __restrict__ Wf, const float* __restrict__ bfv,
                                                    const float* __restrict__ W1, const float* __restrict__ b1,
                                                    const float* __restrict__ W2, const float* __restrict__ b2,
                                                    const float* __restrict__ Wl, const float* __restrict__ bl,
                                                    float* __restrict__ out, float* __restrict__ wsf) {
    run_body<1>(x, pos, Wf, bfv, W1, b1, W2, b2, Wl, bl, out, wsf);
}

__global__ __launch_bounds__(256, 2) void abl_back(const float* __restrict__ x, const float* __restrict__ pos,
                                                   const float* __restrict__ Wf, const float* __restrict__ bfv,
                                                   const float* __restrict__ W1, const float* __restrict__ b1,
                                                   const float* __restrict__ W2, const float* __restrict__ b2,
                                                   const float* __restrict__ Wl, const float* __restrict__ bl,
                                                   float* __restrict__ out, float* __restrict__ wsf) {
    run_body<2>(x, pos, Wf, bfv, W1, b1, W2, b2, Wl, bl, out, wsf);
}

extern "C" void kernel_launch(void* const* d_in, const int* in_sizes, int n_in,
                              void* d_out, int out_size, void* d_ws, size_t ws_size,
                              hipStream_t stream) {
    const float* x   = (const float*)d_in[0];
    const float* pos = (const float*)d_in[1];
    const float* Wf  = (const float*)d_in[2];
    const float* bf  = (const float*)d_in[3];
    const float* W1  = (const float*)d_in[4];
    const float* b1  = (const float*)d_in[5];
    const float* W2  = (const float*)d_in[6];
    const float* b2  = (const float*)d_in[7];
    const float* Wl  = (const float*)d_in[8];
    const float* bl  = (const float*)d_in[9];
    float* out = (float*)d_out;
    float* wsf = (float*)d_ws;

    hipLaunchKernelGGL(fused_full, dim3(512), dim3(256), 0, stream,
                       x, pos, Wf, bf, W1, b1, W2, b2, Wl, bl, out, wsf);
    hipLaunchKernelGGL(abl_front, dim3(512), dim3(256), 0, stream,
                       x, pos, Wf, bf, W1, b1, W2, b2, Wl, bl, out, wsf);
    hipLaunchKernelGGL(abl_back, dim3(512), dim3(256), 0, stream,
                       x, pos, Wf, bf, W1, b1, W2, b2, Wl, bl, out, wsf);
}

// Round 14
// 27.178 us; speedup vs baseline: 2.0901x; 2.0901x over previous
//
#include <hip/hip_runtime.h>
#include <hip/hip_bf16.h>

#define NB 4
#define NN 2048
#define KK 32
#define DD 64
#define R2C 0.64f

typedef __attribute__((ext_vector_type(8)))  short short8;   // 8 bf16 (4 VGPRs)
typedef __attribute__((ext_vector_type(16))) float f32x16;   // 32x32 MFMA acc

__device__ __forceinline__ unsigned short f2bf(float f) {
    __hip_bfloat16 h = __float2bfloat16(f);
    return reinterpret_cast<unsigned short&>(h);
}

#define HSTRIDE 40   // ushorts per h-row in LDS (80B = 5x16B, b128-aligned)

// write relu'd D to LDS, read back transposed as next A-fragments.
// One 2.5KB buffer per wave, reused sequentially (same-wave DS ops are ordered).
__device__ __forceinline__ void post_layer(const f32x16& acc, float bs,
                                           unsigned short* hl, int col, int g,
                                           float& mx, short8& f0, short8& f1) {
    float v[16];
#pragma unroll
    for (int p = 0; p < 16; ++p) v[p] = fmaxf(acc[p] + bs, 0.0f);   // base + relu
    float m = v[0];
#pragma unroll
    for (int p = 1; p < 16; ++p) m = fmaxf(m, v[p]);
    mx = fmaxf(m, __shfl_xor(m, 32));
#pragma unroll
    for (int p = 0; p < 16; ++p) {
        int r = (p & 3) + 8 * (p >> 2) + 4 * g;
        hl[r * HSTRIDE + col] = f2bf(v[p]);
    }
    const unsigned short* row = hl + col * HSTRIDE;
    f0 = *(const short8*)(row + 8 * g);
    f1 = *(const short8*)(row + 16 + 8 * g);
}

// gather 8 consecutive f32 -> bf16 short8 fragment (RNE)
__device__ __forceinline__ short8 cvt8(const float* __restrict__ p) {
    float4 a = ((const float4*)p)[0];
    float4 b = ((const float4*)p)[1];
    short8 r;
    r[0] = (short)f2bf(a.x); r[1] = (short)f2bf(a.y); r[2] = (short)f2bf(a.z); r[3] = (short)f2bf(a.w);
    r[4] = (short)f2bf(b.x); r[5] = (short)f2bf(b.y); r[6] = (short)f2bf(b.z); r[7] = (short)f2bf(b.w);
    return r;
}

__device__ __forceinline__ void l1_mfma(const short8* hf, int lane, const short8* wl, f32x16& acc) {
#pragma unroll
    for (int p = 0; p < 16; ++p) acc[p] = 0.0f;
    acc = __builtin_amdgcn_mfma_f32_32x32x16_bf16(hf[0], wl[4 * 64 + lane], acc, 0, 0, 0);
    acc = __builtin_amdgcn_mfma_f32_32x32x16_bf16(hf[1], wl[5 * 64 + lane], acc, 0, 0, 0);
}

__device__ __forceinline__ void l2_mfma(const short8* h1, const short8* h0,
                                        int lane, const short8* wl, f32x16& acc) {
#pragma unroll
    for (int p = 0; p < 16; ++p) acc[p] = 0.0f;
    acc = __builtin_amdgcn_mfma_f32_32x32x16_bf16(h1[0], wl[6 * 64 + lane], acc, 0, 0, 0);
    acc = __builtin_amdgcn_mfma_f32_32x32x16_bf16(h1[1], wl[7 * 64 + lane], acc, 0, 0, 0);
    acc = __builtin_amdgcn_mfma_f32_32x32x16_bf16(h0[0], wl[8 * 64 + lane], acc, 0, 0, 0);
    acc = __builtin_amdgcn_mfma_f32_32x32x16_bf16(h0[1], wl[9 * 64 + lane], acc, 0, 0, 0);
}

__device__ __forceinline__ void l3_mfma(const short8* h2, const short8* h1, const short8* h0,
                                        int lane, const short8* wl, f32x16& acc) {
#pragma unroll
    for (int p = 0; p < 16; ++p) acc[p] = 0.0f;
    acc = __builtin_amdgcn_mfma_f32_32x32x16_bf16(h2[0], wl[10 * 64 + lane], acc, 0, 0, 0);
    acc = __builtin_amdgcn_mfma_f32_32x32x16_bf16(h2[1], wl[11 * 64 + lane], acc, 0, 0, 0);
    acc = __builtin_amdgcn_mfma_f32_32x32x16_bf16(h1[0], wl[12 * 64 + lane], acc, 0, 0, 0);
    acc = __builtin_amdgcn_mfma_f32_32x32x16_bf16(h1[1], wl[13 * 64 + lane], acc, 0, 0, 0);
    acc = __builtin_amdgcn_mfma_f32_32x32x16_bf16(h0[0], wl[14 * 64 + lane], acc, 0, 0, 0);
    acc = __builtin_amdgcn_mfma_f32_32x32x16_bf16(h0[1], wl[15 * 64 + lane], acc, 0, 0, 0);
}

// 2 queries per wave, 1024 blocks = 4 blocks/CU, LDS 27.6KB -> 16 waves/CU resident.
__global__ __launch_bounds__(256, 4) void fused_kernel(const float* __restrict__ x,
                                                       const float* __restrict__ pos,
                                                       const float* __restrict__ Wf,
                                                       const float* __restrict__ bfv,
                                                       const float* __restrict__ W1,
                                                       const float* __restrict__ b1,
                                                       const float* __restrict__ W2,
                                                       const float* __restrict__ b2,
                                                       const float* __restrict__ Wl,
                                                       const float* __restrict__ bl,
                                                       float* __restrict__ out) {
    __shared__ unsigned short hlds[4][32 * HSTRIDE];      // 10 KB (one per wave, shared by its 2 queries)
    __shared__ int nbrs[4][2][KK];                        // 1 KB
    __shared__ unsigned short lwf[16 * 64 * 8];           // 16 KB
    int wid = threadIdx.x >> 6, lane = threadIdx.x & 63;
    int qp = __builtin_amdgcn_readfirstlane(blockIdx.x * 4 + wid);  // pair index [0,4096)
    int q0 = qp << 1;                               // 2 queries per wave, same batch
    int col = lane & 31, g = lane >> 5;
    int b = q0 >> 11, n0 = q0 & (NN - 1);

    // ---- cooperative wfrag build into LDS ----
    for (int e = threadIdx.x; e < 1024; e += 256) {
        int f = e >> 6, l = e & 63;
        int c = l & 31, g2 = l >> 5;
        unsigned short* dst = lwf + (size_t)(f * 64 + l) * 8;
#pragma unroll
        for (int j = 0; j < 8; ++j) {
            int kl = 8 * g2 + j;
            float v;
            if (f < 4)       { int rr = 16 * f + kl;             v = Wf[(64 + rr) * 32 + c] + Wf[(128 + rr) * 32 + c]; }
            else if (f < 6)  { int rr = 16 * (f - 4) + kl;       v = W1[rr * 32 + c]; }
            else if (f < 8)  { int rr = 16 * (f - 6) + kl;       v = W2[rr * 32 + c]; }
            else if (f < 10) { int rr = 32 + 16 * (f - 8) + kl;  v = W2[rr * 32 + c]; }
            else if (f < 12) { int rr = 16 * (f - 10) + kl;      v = Wl[rr * 32 + c]; }
            else if (f < 14) { int rr = 32 + 16 * (f - 12) + kl; v = Wl[rr * 32 + c]; }
            else             { int rr = 64 + 16 * (f - 14) + kl; v = Wl[rr * 32 + c]; }
            dst[j] = f2bf(v);
        }
    }

    // ---- bases from RAW weights (coalesced per half-wave), 4 independent FMA chains ----
    const float* xq0 = x + (size_t)q0 * DD;
    bool lo = lane < 32;
    int c0 = lane & 31;
    const float* pA1 = lo ? (Wf + c0) : (W1 + 32 * 32 + c0);
    const float* pA2 = lo ? (Wf + 128 * 32 + c0) : (W1 + 32 * 32 + c0);
    float sA = lo ? -1.0f : 0.0f;
    const float* pB1 = lo ? (W2 + 64 * 32 + c0) : (Wl + 96 * 32 + c0);
    float balA = lo ? bfv[c0] : b1[c0];
    float balB = lo ? b2[c0] : bl[c0];
    float aA[2] = {balA, balA};
    float aB[2] = {balB, balB};
#pragma unroll
    for (int j0 = 0; j0 < 16; ++j0) {
        float wa[4], wb[4];
#pragma unroll
        for (int jj = 0; jj < 4; ++jj) {
            int j = 4 * j0 + jj;
            wa[jj] = fmaf(sA, pA2[j * 32], pA1[j * 32]);
            wb[jj] = pB1[j * 32];
        }
#pragma unroll
        for (int t = 0; t < 2; ++t) {
            const float* xr = xq0 + t * DD + 4 * j0;
            float x0 = xr[0], x1 = xr[1], x2 = xr[2], x3 = xr[3];
            aA[t] = fmaf(x0, wa[0], aA[t]); aA[t] = fmaf(x1, wa[1], aA[t]);
            aA[t] = fmaf(x2, wa[2], aA[t]); aA[t] = fmaf(x3, wa[3], aA[t]);
            aB[t] = fmaf(x0, wb[0], aB[t]); aB[t] = fmaf(x1, wb[1], aB[t]);
            aB[t] = fmaf(x2, wb[2], aB[t]); aB[t] = fmaf(x3, wb[3], aB[t]);
        }
    }
    float bs0[2], bs1[2], bs2[2], bs3[2];
#pragma unroll
    for (int t = 0; t < 2; ++t) {
        bs0[t] = __shfl(aA[t], col, 64); bs1[t] = __shfl(aA[t], 32 + col, 64);
        bs2[t] = __shfl(aB[t], col, 64); bs3[t] = __shfl(aB[t], 32 + col, 64);
    }

    // ---- shared-chunk ball query (exact reference arithmetic) ----
    const float* pb = pos + (size_t)b * NN * 3;
    float qxv[2], qyv[2], qzv[2], sq4[2];
#pragma unroll
    for (int t = 0; t < 2; ++t) {
        int n = n0 + t;
        qxv[t] = pb[3 * n]; qyv[t] = pb[3 * n + 1]; qzv[t] = pb[3 * n + 2];
        sq4[t] = __fadd_rn(__fadd_rn(__fmul_rn(qxv[t], qxv[t]), __fmul_rn(qyv[t], qyv[t])),
                           __fmul_rn(qzv[t], qzv[t]));
    }
    int cnt[2] = {0, 0};
    unsigned long long ltmask = (1ULL << lane) - 1ULL;
    for (int m0 = 0; m0 < NN; m0 += 64) {
        if (cnt[0] >= KK && cnt[1] >= KK) break;
        int m = m0 + lane;
        float mx3 = pb[3 * m], my3 = pb[3 * m + 1], mz3 = pb[3 * m + 2];
        float sqm = __fadd_rn(__fadd_rn(__fmul_rn(mx3, mx3), __fmul_rn(my3, my3)), __fmul_rn(mz3, mz3));
#pragma unroll
        for (int t = 0; t < 2; ++t) {
            if (cnt[t] < KK) {
                float dot = __fadd_rn(__fadd_rn(__fmul_rn(qxv[t], mx3), __fmul_rn(qyv[t], my3)),
                                      __fmul_rn(qzv[t], mz3));
                float d2 = __fsub_rn(__fadd_rn(sq4[t], sqm), __fmul_rn(2.0f, dot));
                bool hit = d2 < R2C;
                unsigned long long mask = __ballot(hit);
                if (hit) {
                    int p = cnt[t] + (int)__popcll(mask & ltmask);
                    if (p < KK) nbrs[wid][t][p] = m;
                }
                cnt[t] = __builtin_amdgcn_readfirstlane(cnt[t] + (int)__popcll(mask));
            }
        }
    }
    int nbn[2];
#pragma unroll
    for (int t = 0; t < 2; ++t) nbn[t] = nbrs[wid][t][col < cnt[t] ? col : 0];

    // ---- gather neighbor rows, cvt to bf16 in-register ----
    short8 xk[2][4];
#pragma unroll
    for (int t = 0; t < 2; ++t) {
        const float* xrow = x + (size_t)(b * NN + nbn[t]) * DD + g * 8;
#pragma unroll
        for (int kf = 0; kf < 4; ++kf) xk[t][kf] = cvt8(xrow + kf * 16);
    }

    __syncthreads();     // lwf ready
    const short8* wl = (const short8*)lwf;
    unsigned short* hl = hlds[wid];

    f32x16 a0, a1;
    float mx0[2], mx1[2], mx2[2];
    short8 h0f[2][2], h1f[2][2], h2f[2][2];

    // ---- L0 ----
#pragma unroll
    for (int p = 0; p < 16; ++p) { a0[p] = 0.0f; a1[p] = 0.0f; }
#pragma unroll
    for (int f = 0; f < 4; ++f) a0 = __builtin_amdgcn_mfma_f32_32x32x16_bf16(xk[0][f], wl[f * 64 + lane], a0, 0, 0, 0);
#pragma unroll
    for (int f = 0; f < 4; ++f) a1 = __builtin_amdgcn_mfma_f32_32x32x16_bf16(xk[1][f], wl[f * 64 + lane], a1, 0, 0, 0);
    post_layer(a0, bs0[0], hl, col, g, mx0[0], h0f[0][0], h0f[0][1]);
    post_layer(a1, bs0[1], hl, col, g, mx0[1], h0f[1][0], h0f[1][1]);

    // ---- L1 ----
    l1_mfma(h0f[0], lane, wl, a0);
    l1_mfma(h0f[1], lane, wl, a1);
    post_layer(a0, bs1[0], hl, col, g, mx1[0], h1f[0][0], h1f[0][1]);
    post_layer(a1, bs1[1], hl, col, g, mx1[1], h1f[1][0], h1f[1][1]);

    // ---- L2 ----
    l2_mfma(h1f[0], h0f[0], lane, wl, a0);
    l2_mfma(h1f[1], h0f[1], lane, wl, a1);
    post_layer(a0, bs2[0], hl, col, g, mx2[0], h2f[0][0], h2f[0][1]);
    post_layer(a1, bs2[1], hl, col, g, mx2[1], h2f[1][0], h2f[1][1]);

    // ---- L3 (no relu) ----
    float m3[2];
    l3_mfma(h2f[0], h1f[0], h0f[0], lane, wl, a0);
    l3_mfma(h2f[1], h1f[1], h0f[1], lane, wl, a1);
    {
        float m = a0[0] + bs3[0];
#pragma unroll
        for (int p = 1; p < 16; ++p) m = fmaxf(m, a0[p] + bs3[0]);
        m3[0] = fmaxf(m, __shfl_xor(m, 32));
    }
    {
        float m = a1[0] + bs3[1];
#pragma unroll
        for (int p = 1; p < 16; ++p) m = fmaxf(m, a1[p] + bs3[1]);
        m3[1] = fmaxf(m, __shfl_xor(m, 32));
    }

    // ---- store: out rows = [h3, h2, h1, h0, x] ----
#pragma unroll
    for (int t = 0; t < 2; ++t) {
        float* o = out + (size_t)(q0 + t) * 192;
        if (g == 0) {
            o[col]      = m3[t];
            o[32 + col] = mx2[t];
            o[64 + col] = mx1[t];
            o[96 + col] = mx0[t];
        }
        o[128 + lane] = xq0[t * DD + lane];   // x passthrough
    }
}

extern "C" void kernel_launch(void* const* d_in, const int* in_sizes, int n_in,
                              void* d_out, int out_size, void* d_ws, size_t ws_size,
                              hipStream_t stream) {
    const float* x   = (const float*)d_in[0];
    const float* pos = (const float*)d_in[1];
    const float* Wf  = (const float*)d_in[2];
    const float* bf  = (const float*)d_in[3];
    const float* W1  = (const float*)d_in[4];
    const float* b1  = (const float*)d_in[5];
    const float* W2  = (const float*)d_in[6];
    const float* b2  = (const float*)d_in[7];
    const float* Wl  = (const float*)d_in[8];
    const float* bl  = (const float*)d_in[9];
    float* out = (float*)d_out;

    hipLaunchKernelGGL(fused_kernel, dim3(1024), dim3(256), 0, stream,
                       x, pos, Wf, bf, W1, b1, W2, b2, Wl, bl, out);
}